// Round 9
// baseline (665.335 us; speedup 1.0000x reference)
//
#include <hip/hip_runtime.h>
#include <math.h>

#define BB 2
#define LL 2048
#define SS 2048
#define HH 8
#define EE 64
#define DD 64
#define HE (HH * EE)   // 512
// softmax scale = 1/sqrt(E) = 0.125

// ws layout (384 KB):
//   [0, 128K)     : m32  (B*H*L floats) -- BLAS-grid fp32 M_sp (bit-exact)
//   [128K, 256K)  : rank (B*H*L ints)
//   [256K, 384K)  : maxs (B*H*L floats)

typedef __attribute__((ext_vector_type(8))) short   bf16x8;   // MFMA A/B frag
typedef __attribute__((ext_vector_type(4))) float   f32x4;    // MFMA C/D frag
typedef __attribute__((ext_vector_type(8))) unsigned short u16x8;
typedef __attribute__((ext_vector_type(4))) unsigned short u16x4;

__device__ __forceinline__ unsigned short f2bf(float x) {   // fp32 -> bf16 RNE
    unsigned int u = __float_as_uint(x);
    return (unsigned short)((u + 0x7FFFu + ((u >> 16) & 1u)) >> 16);
}

__device__ __forceinline__ float rdlane(float v, int lane) { // bit-exact copy
    return __uint_as_float(
        (unsigned)__builtin_amdgcn_readlane((int)__float_as_uint(v), lane));
}

// ---------- A: BLAS-grid fp32 M_sp, VMEM + readlane broadcast, 2 q/lane ---
// Arithmetic sequence IDENTICAL to the verified kernel, applied per query:
// score = sequential fmaf chain e=0..63 asc, single accumulator (each c[j]/
// d[j] chain receives its updates in ascending-e order; the j/e4 loop
// nesting only interleaves INDEPENDENT chains); r[j] chain over i8=0..15
// sequential; blk[lf] = exact-halves tree over r[0..7];
// sub = ((blk0+blk1)+(blk2+blk3)); s2048 = ((sub0+sub1)+(sub2+sub3)).
// DO NOT REORDER. readlane is a bit-exact copy.
//
// R8 analysis: v_readlane issues at ~4cyc (cross-lane, half rate) -> with
// 1 query/lane the 1:1 readlane:fmac ratio doubles VALU time (188us busy).
// Here each lane owns TWO queries (qf0: row lt*128+lq, qf1: +64) so each
// readlane feeds 2 fmacs: per-SIMD VALU 393k -> 262k cyc (164 -> 109us).
// Cost: qf0+qf1 = 128 VGPR -> 1 wave/SIMD (R1-R7 occupancy model:
// 2 waves need VGPR<=128). Acceptable because ALL hot work is on the VALU
// pipe: 16 independent acc chains keep the pipe full, and the one-group-
// ahead VMEM prefetch (compute/group ~4k cyc >> 900cyc HBM) hides memory.
// launch_bounds(256,1): 256-VGPR cap, est ~200 used, no spill (R4: 172 ok;
// R5 lesson: never >=512-thread blocks).
__global__ __launch_bounds__(256, 1)
void msp_blas(const float* __restrict__ Q, const float* __restrict__ K,
              float* __restrict__ m32, float* __restrict__ maxs) {
#pragma clang fp contract(off)
    const int bid = blockIdx.x;          // B*H*16 = 256
    const int lt = bid & 15, bh = bid >> 4;
    const int h = bh & 7, b = bh >> 3;
    const int t = threadIdx.x, lq = t & 63, w = t >> 6;   // w = 0..3
    const int l0 = lt * 128 + lq;        // first query of this lane
    const int l1 = l0 + 64;              // second query of this lane

    float qf0[64], qf1[64];
    {
        const float4* q0 = (const float4*)(Q + (((size_t)b * LL + l0) * HH + h) * EE);
        const float4* q1 = (const float4*)(Q + (((size_t)b * LL + l1) * HH + h) * EE);
#pragma unroll
        for (int i = 0; i < 16; i++) {
            float4 v = q0[i];
            qf0[4*i] = v.x; qf0[4*i+1] = v.y; qf0[4*i+2] = v.z; qf0[4*i+3] = v.w;
        }
#pragma unroll
        for (int i = 0; i < 16; i++) {
            float4 v = q1[i];
            qf1[4*i] = v.x; qf1[4*i+1] = v.y; qf1[4*i+2] = v.z; qf1[4*i+3] = v.w;
        }
    }

    // wave w owns keys [512w, 512w+512) (same blk mapping as verified kernel)
    const float* Kw = K + (((size_t)b * SS) * HH + h) * EE + (size_t)w * 512 * HE;
    // per-lane load base: key +(lq>>4), floats 4*(lq&15)..+3 (coalesced 256B)
    const float* gld = Kw + (size_t)(lq >> 4) * HE + (lq & 15) * 4;

    // double-buffered 8-key groups: A = keys kc..kc+3, B = keys kc+4..kc+7
    float4 A0 = *(const float4*)(gld);
    float4 B0 = *(const float4*)(gld + 4 * HE);

    float mx0 = -1e30f, mx1 = -1e30f;
    float blk0[4], blk1[4];
#pragma unroll 1
    for (int lf = 0; lf < 4; ++lf) {
        float r0[8], r1[8];
#pragma unroll 1
        for (int i8 = 0; i8 < 16; ++i8) {
            const int kc = lf * 128 + i8 * 8;            // group base key
            const int kn = (kc < 504) ? kc + 8 : 504;    // next (tail: reload)

            // issue next-group loads; consumed only at the A0=A1 copy below
            float4 A1 = *(const float4*)(gld + (size_t)kn * HE);
            float4 B1 = *(const float4*)(gld + (size_t)(kn + 4) * HE);

            float c[8], d[8];
#pragma unroll
            for (int j = 0; j < 8; ++j) { c[j] = 0.f; d[j] = 0.f; }
            // e4 outer / j inner: interleaves 16 independent chains; each
            // chain still strictly e-ascending (bit-exact).
#pragma unroll
            for (int e4 = 0; e4 < 16; ++e4) {
#pragma unroll
                for (int j = 0; j < 4; ++j) {
                    const int ln = j * 16 + e4;
                    const float sx = rdlane(A0.x, ln);
                    const float sy = rdlane(A0.y, ln);
                    const float sz = rdlane(A0.z, ln);
                    const float sw = rdlane(A0.w, ln);
                    c[j] = fmaf(qf0[4*e4+0], sx, c[j]);
                    c[j] = fmaf(qf0[4*e4+1], sy, c[j]);
                    c[j] = fmaf(qf0[4*e4+2], sz, c[j]);
                    c[j] = fmaf(qf0[4*e4+3], sw, c[j]);
                    d[j] = fmaf(qf1[4*e4+0], sx, d[j]);
                    d[j] = fmaf(qf1[4*e4+1], sy, d[j]);
                    d[j] = fmaf(qf1[4*e4+2], sz, d[j]);
                    d[j] = fmaf(qf1[4*e4+3], sw, d[j]);
                }
            }
#pragma unroll
            for (int e4 = 0; e4 < 16; ++e4) {
#pragma unroll
                for (int j = 0; j < 4; ++j) {
                    const int ln = j * 16 + e4;
                    const float sx = rdlane(B0.x, ln);
                    const float sy = rdlane(B0.y, ln);
                    const float sz = rdlane(B0.z, ln);
                    const float sw = rdlane(B0.w, ln);
                    c[4+j] = fmaf(qf0[4*e4+0], sx, c[4+j]);
                    c[4+j] = fmaf(qf0[4*e4+1], sy, c[4+j]);
                    c[4+j] = fmaf(qf0[4*e4+2], sz, c[4+j]);
                    c[4+j] = fmaf(qf0[4*e4+3], sw, c[4+j]);
                    d[4+j] = fmaf(qf1[4*e4+0], sx, d[4+j]);
                    d[4+j] = fmaf(qf1[4*e4+1], sy, d[4+j]);
                    d[4+j] = fmaf(qf1[4*e4+2], sz, d[4+j]);
                    d[4+j] = fmaf(qf1[4*e4+3], sw, d[4+j]);
                }
            }
#pragma unroll
            for (int j = 0; j < 8; ++j) {
                mx0 = fmaxf(mx0, c[j]);
                mx1 = fmaxf(mx1, d[j]);
                if (i8 == 0) { r0[j] = c[j];               r1[j] = d[j]; }
                else         { r0[j] = __fadd_rn(r0[j], c[j]);
                               r1[j] = __fadd_rn(r1[j], d[j]); }
            }
            A0 = A1; B0 = B1;   // vmcnt wait lands here, after compute
        }
        blk0[lf] = __fadd_rn(
            __fadd_rn(__fadd_rn(r0[0], r0[1]), __fadd_rn(r0[2], r0[3])),
            __fadd_rn(__fadd_rn(r0[4], r0[5]), __fadd_rn(r0[6], r0[7])));
        blk1[lf] = __fadd_rn(
            __fadd_rn(__fadd_rn(r1[0], r1[1]), __fadd_rn(r1[2], r1[3])),
            __fadd_rn(__fadd_rn(r1[4], r1[5]), __fadd_rn(r1[6], r1[7])));
    }
    const float sub0 = __fadd_rn(__fadd_rn(blk0[0], blk0[1]),
                                 __fadd_rn(blk0[2], blk0[3]));
    const float sub1 = __fadd_rn(__fadd_rn(blk1[0], blk1[1]),
                                 __fadd_rn(blk1[2], blk1[3]));

    __shared__ float smx[2][4][64], ssub[2][4][64];
    smx[0][w][lq] = mx0; ssub[0][w][lq] = sub0;
    smx[1][w][lq] = mx1; ssub[1][w][lq] = sub1;
    __syncthreads();
    if (w < 2) {     // wave 0 finalizes query half 0, wave 1 half 1
        const int half = w;
        const float m_all = fmaxf(fmaxf(smx[half][0][lq], smx[half][1][lq]),
                                  fmaxf(smx[half][2][lq], smx[half][3][lq]));
        const float s2048 = __fadd_rn(
            __fadd_rn(ssub[half][0][lq], ssub[half][1][lq]),
            __fadd_rn(ssub[half][2][lq], ssub[half][3][lq]));
        const float mean = __fmul_rn(s2048, 0.00048828125f);  // /2048 exact
        const int l = lt * 128 + half * 64 + lq;
        m32[((size_t)bh << 11) + l]  = __fsub_rn(m_all, mean);
        maxs[((size_t)bh << 11) + l] = m_all;
    }
}

// ---------- B: descending sort, ties -> lower index first -----------------
__global__ __launch_bounds__(256)
void sort_rank(const float* __restrict__ m32, int* __restrict__ rank) {
    __shared__ unsigned int k1[2048];
    __shared__ int pay[2048];
    const int bh = blockIdx.x;
    const int t = threadIdx.x;
    for (int i = t; i < 2048; i += 256) {
        unsigned int u = __float_as_uint(m32[((size_t)bh << 11) + i]);
        u = (u & 0x80000000u) ? ~u : (u | 0x80000000u);
        k1[i] = u; pay[i] = i;
    }
    __syncthreads();
    for (int k = 2; k <= 2048; k <<= 1) {
        for (int j = k >> 1; j > 0; j >>= 1) {
            for (int i = t; i < 2048; i += 256) {
                const int ixj = i ^ j;
                if (ixj > i) {
                    unsigned int a1 = k1[i], c1 = k1[ixj];
                    int pa = pay[i], pc = pay[ixj];
                    const bool pre = (a1 > c1) || (a1 == c1 && pa < pc);
                    const bool dir = ((i & k) == 0);
                    if (dir != pre) {
                        k1[i] = c1; k1[ixj] = a1;
                        pay[i] = pc; pay[ixj] = pa;
                    }
                }
            }
            __syncthreads();
        }
    }
    for (int i = t; i < 2048; i += 256)
        rank[((size_t)bh << 11) + pay[i]] = i;   // inverse permutation
}

// ---------- C: bf16 MFMA flash (two-pass softmax), scatter by rank --------
// Wave w owns 16 queries (rows lt*64 + w*16 .. +15) over the FULL S range.
// Per 64-s chunk: QK via mfma_16x16x32_bf16 (8), exp, P->LDS (A-layout),
// PV via mfma (8). K staged [s][e], V staged transposed [d][s], pitch 72
// bf16 (16B-aligned rows, bank-spread).
__global__ __launch_bounds__(256, 2)
void flash_mfma(const float* __restrict__ Q, const float* __restrict__ K,
                const float* __restrict__ V, const float* __restrict__ maxs,
                const int* __restrict__ rank, float* __restrict__ out) {
    __shared__ unsigned short ldsK[64 * 72];        // 9216 B
    __shared__ unsigned short ldsVT[64 * 72];       // 9216 B  (V transposed)
    __shared__ unsigned short ldsP[4 * 16 * 72];    // 9216 B  (per-wave P)

    const int bid = blockIdx.x;          // 512
    const int lt = bid & 31, bh = bid >> 5;
    const int h = bh & 7, b = bh >> 3;
    const int t = threadIdx.x, lane = t & 63, w = t >> 6;
    const int quad = lane >> 4, cl = lane & 15;

    const size_t kvbase = (((size_t)b * SS) * HH + h) * EE;

    // Q A-frags: A[m=cl][k=quad*8+j (+32*ef)]
    bf16x8 qa[2];
    {
        const float* qp = Q + (((size_t)b * LL + (lt * 64 + w * 16 + cl)) * HH + h) * EE
                          + quad * 8;
#pragma unroll
        for (int ef = 0; ef < 2; ++ef) {
            float4 a0 = *(const float4*)(qp + ef * 32);
            float4 a1 = *(const float4*)(qp + ef * 32 + 4);
            short* s = (short*)&qa[ef];
            s[0] = (short)f2bf(a0.x); s[1] = (short)f2bf(a0.y);
            s[2] = (short)f2bf(a0.z); s[3] = (short)f2bf(a0.w);
            s[4] = (short)f2bf(a1.x); s[5] = (short)f2bf(a1.y);
            s[6] = (short)f2bf(a1.z); s[7] = (short)f2bf(a1.w);
        }
    }

    // per-lane row constants (rows quad*4+reg)
    float negpm[4];
    int rk[4];
#pragma unroll
    for (int reg = 0; reg < 4; ++reg) {
        const int qg = lt * 64 + w * 16 + quad * 4 + reg;
        negpm[reg] = -0.125f * maxs[((size_t)bh << 11) + qg];
        rk[reg]    = rank[((size_t)bh << 11) + qg];
    }

    f32x4 accO[4];
#pragma unroll
    for (int nt = 0; nt < 4; ++nt) accO[nt] = (f32x4){0.f, 0.f, 0.f, 0.f};
    float ell[4] = {0.f, 0.f, 0.f, 0.f};

    const int pbase = w * (16 * 72);

#pragma unroll 1
    for (int c0 = 0; c0 < SS; c0 += 64) {
        __syncthreads();
        // ---- stage K[s][e] -> bf16, row-major pitch 72 ----
        {
            const int row = t >> 2, col0 = (t & 3) * 16;
            const float* gp = K + kvbase + (size_t)(c0 + row) * HE + col0;
            float4 f0 = ((const float4*)gp)[0];
            float4 f1 = ((const float4*)gp)[1];
            float4 f2 = ((const float4*)gp)[2];
            float4 f3 = ((const float4*)gp)[3];
            u16x8 w0 = { f2bf(f0.x), f2bf(f0.y), f2bf(f0.z), f2bf(f0.w),
                         f2bf(f1.x), f2bf(f1.y), f2bf(f1.z), f2bf(f1.w) };
            u16x8 w1 = { f2bf(f2.x), f2bf(f2.y), f2bf(f2.z), f2bf(f2.w),
                         f2bf(f3.x), f2bf(f3.y), f2bf(f3.z), f2bf(f3.w) };
            *(u16x8*)&ldsK[row * 72 + col0]     = w0;
            *(u16x8*)&ldsK[row * 72 + col0 + 8] = w1;
        }
        // ---- stage V transposed: VT[d][s] bf16, pitch 72 ----
        {
            const int s0 = (t & 15) * 4, d0 = (t >> 4) * 4;
            const float* gv = V + kvbase + (size_t)(c0 + s0) * HE + d0;
            float4 v0 = *(const float4*)(gv);
            float4 v1 = *(const float4*)(gv + HE);
            float4 v2 = *(const float4*)(gv + 2 * HE);
            float4 v3 = *(const float4*)(gv + 3 * HE);
            u16x4 p0 = { f2bf(v0.x), f2bf(v1.x), f2bf(v2.x), f2bf(v3.x) };
            u16x4 p1 = { f2bf(v0.y), f2bf(v1.y), f2bf(v2.y), f2bf(v3.y) };
            u16x4 p2 = { f2bf(v0.z), f2bf(v1.z), f2bf(v2.z), f2bf(v3.z) };
            u16x4 p3 = { f2bf(v0.w), f2bf(v1.w), f2bf(v2.w), f2bf(v3.w) };
            *(u16x4*)&ldsVT[(d0 + 0) * 72 + s0] = p0;
            *(u16x4*)&ldsVT[(d0 + 1) * 72 + s0] = p1;
            *(u16x4*)&ldsVT[(d0 + 2) * 72 + s0] = p2;
            *(u16x4*)&ldsVT[(d0 + 3) * 72 + s0] = p3;
        }
        __syncthreads();

        // ---- QK^T: S[m=q16][n=s64] = A(Q) x B(K), B[k=e][n=s]=K[s][e] ----
        f32x4 Sc[4];
#pragma unroll
        for (int nt = 0; nt < 4; ++nt) {
            bf16x8 bk0 = *(const bf16x8*)&ldsK[(nt * 16 + cl) * 72 + quad * 8];
            bf16x8 bk1 = *(const bf16x8*)&ldsK[(nt * 16 + cl) * 72 + quad * 8 + 32];
            f32x4 z = (f32x4){0.f, 0.f, 0.f, 0.f};
            z = __builtin_amdgcn_mfma_f32_16x16x32_bf16(qa[0], bk0, z, 0, 0, 0);
            z = __builtin_amdgcn_mfma_f32_16x16x32_bf16(qa[1], bk1, z, 0, 0, 0);
            Sc[nt] = z;
        }

        // ---- softmax numerator + P (bf16) into A-layout LDS ----
#pragma unroll
        for (int nt = 0; nt < 4; ++nt) {
#pragma unroll
            for (int reg = 0; reg < 4; ++reg) {
                const float p = __expf(fmaf(Sc[nt][reg], 0.125f, negpm[reg]));
                ell[reg] += p;
                ldsP[pbase + (quad * 4 + reg) * 72 + nt * 16 + cl] = f2bf(p);
            }
        }

        // ---- PV: O[m=q16][n=d64] += A(P) x B(V), B[k=s][n=d]=VT[d][s] ----
        bf16x8 pa0 = *(const bf16x8*)&ldsP[pbase + cl * 72 + quad * 8];
        bf16x8 pa1 = *(const bf16x8*)&ldsP[pbase + cl * 72 + quad * 8 + 32];
#pragma unroll
        for (int nt = 0; nt < 4; ++nt) {
            bf16x8 bv0 = *(const bf16x8*)&ldsVT[(nt * 16 + cl) * 72 + quad * 8];
            bf16x8 bv1 = *(const bf16x8*)&ldsVT[(nt * 16 + cl) * 72 + quad * 8 + 32];
            accO[nt] = __builtin_amdgcn_mfma_f32_16x16x32_bf16(pa0, bv0, accO[nt], 0, 0, 0);
            accO[nt] = __builtin_amdgcn_mfma_f32_16x16x32_bf16(pa1, bv1, accO[nt], 0, 0, 0);
        }
    }

    // ---- ell: reduce across the 16 lanes sharing each row (within quad) ----
#pragma unroll
    for (int reg = 0; reg < 4; ++reg) {
        float e = ell[reg];
        e += __shfl_xor(e, 1);
        e += __shfl_xor(e, 2);
        e += __shfl_xor(e, 4);
        e += __shfl_xor(e, 8);
        ell[reg] = 1.0f / e;
    }

    // ---- scatter O rows by rank ----
#pragma unroll
    for (int reg = 0; reg < 4; ++reg) {
        float* orow = out + (((size_t)b * LL + rk[reg]) * HH + h) * DD;
#pragma unroll
        for (int nt = 0; nt < 4; ++nt)
            orow[nt * 16 + cl] = accO[nt][reg] * ell[reg];
    }
}

extern "C" void kernel_launch(void* const* d_in, const int* in_sizes, int n_in,
                              void* d_out, int out_size, void* d_ws, size_t ws_size,
                              hipStream_t stream) {
    const float* Q = (const float*)d_in[0];
    const float* K = (const float*)d_in[1];
    const float* V = (const float*)d_in[2];
    float* out = (float*)d_out;

    float* m32  = (float*)d_ws;                          // 128 KB
    int*   rank = (int*)((char*)d_ws + 131072);          // 128 KB
    float* maxs = (float*)((char*)d_ws + 262144);        // 128 KB

    msp_blas<<<BB * HH * (LL / 128), 256, 0, stream>>>(Q, K, m32, maxs);
    sort_rank<<<BB * HH, 256, 0, stream>>>(m32, rank);
    flash_mfma<<<BB * HH * (LL / 64), 256, 0, stream>>>(Q, K, V, maxs, rank, out);
}

// Round 10
// 440.072 us; speedup vs baseline: 1.5119x; 1.5119x over previous
//
#include <hip/hip_runtime.h>
#include <math.h>

#define BB 2
#define LL 2048
#define SS 2048
#define HH 8
#define EE 64
#define DD 64
#define HE (HH * EE)   // 512
// softmax scale = 1/sqrt(E) = 0.125

// ws layout (384 KB):
//   [0, 128K)     : m32  (B*H*L floats) -- BLAS-grid fp32 M_sp (bit-exact)
//   [128K, 256K)  : rank (B*H*L ints)
//   [256K, 384K)  : maxs (B*H*L floats)

typedef __attribute__((ext_vector_type(8))) short   bf16x8;   // MFMA A/B frag
typedef __attribute__((ext_vector_type(4))) float   f32x4;    // MFMA C/D frag
typedef __attribute__((ext_vector_type(8))) unsigned short u16x8;
typedef __attribute__((ext_vector_type(4))) unsigned short u16x4;

__device__ __forceinline__ unsigned short f2bf(float x) {   // fp32 -> bf16 RNE
    unsigned int u = __float_as_uint(x);
    return (unsigned short)((u + 0x7FFFu + ((u >> 16) & 1u)) >> 16);
}

__device__ __forceinline__ float rdlane(float v, int lane) { // bit-exact copy
    return __uint_as_float(
        (unsigned)__builtin_amdgcn_readlane((int)__float_as_uint(v), lane));
}

// ---------- A: BLAS-grid fp32 M_sp, HYBRID broadcast: LDS pipe + readlane -
// Arithmetic sequence IDENTICAL to the verified kernel:
// score = sequential fmaf chain e=0..63 asc, single accumulator; r[j] chain
// over i8=0..15 sequential; blk[lf] = exact-halves tree over r[0..7];
// sub = ((blk0+blk1)+(blk2+blk3)); s2048 = ((sub0+sub1)+(sub2+sub3)).
// DO NOT REORDER. Both broadcast paths are bit-exact copies.
//
// R8 (218us, proven): pure readlane -> VALU-bound, 1:1 readlane:fmaf,
// readlane ~4.7cyc. LDS pipe idle. R1 (347us, proven): pure LDS broadcast
// -> LDS-pipe-bound at 786k cyc/CU. DIFFERENT PIPES -> split the work:
// per lf (128 keys), i8 groups 0..5 (keys 0..47) via R1's per-wave LDS
// double-buffered chunks; i8 groups 6..15 (keys 48..127) via R8's
// readlane groups. Balance: LDS 0.375*786k=295k cyc/CU vs VALU
// 131k+0.625*308k=324k cyc/SIMD -> ~135us ideal.
// R9 lesson: 2q/lane needs >128 VGPR -> AGPR-spill churn; stay 1q/lane.
// LDS 34816 B = R1's exact footprint (co-resides 2 blocks/CU, 22.5% occ).
// launch_bounds(256,2): 128-VGPR cap; est ~110 (R8 base 84 + staging).
__global__ __launch_bounds__(256, 2)
void msp_blas(const float* __restrict__ Q, const float* __restrict__ K,
              float* __restrict__ m32, float* __restrict__ maxs) {
#pragma clang fp contract(off)
    __shared__ __align__(16) float ldsK[4][2][16 * 64];   // 32 KB, per-wave dbuf
    __shared__ float smx[4][64], ssub[4][64];             // 2 KB

    const int bid = blockIdx.x;          // B*H*32 = 512
    const int lt = bid & 31, bh = bid >> 5;
    const int h = bh & 7, b = bh >> 3;
    const int t = threadIdx.x, lq = t & 63, w = t >> 6;
    const int l = lt * 64 + lq;

    float qf[64];
    const float4* qrow = (const float4*)(Q + (((size_t)b * LL + l) * HH + h) * EE);
#pragma unroll
    for (int i = 0; i < 16; i++) {
        float4 v = qrow[i];
        qf[4*i] = v.x; qf[4*i+1] = v.y; qf[4*i+2] = v.z; qf[4*i+3] = v.w;
    }

    const int wu = __builtin_amdgcn_readfirstlane(w);
    const float* Kb = K + (((size_t)b * SS) * HH + h) * EE;

    // readlane-path load base (R8): 4 keys per dwordx4, coalesced 256B
    const float* gld = Kb + (size_t)(w * 512 + (lq >> 4)) * HE + (lq & 15) * 4;
    // LDS-path staging base (R1): lane covers key row (lq>>2), col (lq&3)*4
    const float* gstage = Kb + (size_t)(wu * 512 + (lq >> 2)) * HE + (lq & 3) * 4;
    const int lslot = (lq >> 2) * 64 + (lq & 3) * 4;

    float4 pf0, pf1, pf2, pf3;
    {   // prologue: LDS chunk seq 0 (lf0, keys 0..15) -> buf 0
        const float* s = gstage;
        pf0 = *(const float4*)(s);
        pf1 = *(const float4*)(s + 16);
        pf2 = *(const float4*)(s + 32);
        pf3 = *(const float4*)(s + 48);
        float* dst = &ldsK[wu][0][lslot];
        *(float4*)(dst)      = pf0;
        *(float4*)(dst + 16) = pf1;
        *(float4*)(dst + 32) = pf2;
        *(float4*)(dst + 48) = pf3;
    }
    // prologue: first readlane group (lf0, i8=6), keys 48..55
    float4 A0 = *(const float4*)(gld + (size_t)48 * HE);
    float4 B0 = *(const float4*)(gld + (size_t)52 * HE);

    float mx = -1e30f;
    float blk[4];
#pragma unroll 1
    for (int lf = 0; lf < 4; ++lf) {
        float r[8];
        // ---- LDS chunks lc = 0..2  (i8 = 0..5, keys lf*128 + 0..47) ----
#pragma unroll 1
        for (int lc = 0; lc < 3; ++lc) {
            const int s_cur = lf * 3 + lc;                 // chunk seq 0..11
            const int s_nxt = (s_cur < 11) ? s_cur + 1 : 11;  // tail: reload
            const int kbn = (s_nxt / 3) * 128 + (s_nxt % 3) * 16;

            // issue next-chunk staging loads (land after compute)
            const float* sp = gstage + (size_t)kbn * HE;
            pf0 = *(const float4*)(sp);
            pf1 = *(const float4*)(sp + 16);
            pf2 = *(const float4*)(sp + 32);
            pf3 = *(const float4*)(sp + 48);

            const float* kb = &ldsK[wu][s_cur & 1][0];
#pragma unroll 1
            for (int i2 = 0; i2 < 2; ++i2) {
                const int i8 = lc * 2 + i2;                // 0..5
                float c[8];
#pragma unroll
                for (int j = 0; j < 8; j++) c[j] = 0.f;
#pragma unroll
                for (int e4 = 0; e4 < 16; ++e4) {
#pragma unroll
                    for (int j = 0; j < 8; j++) {
                        const float4 kv =
                            *(const float4*)&kb[(i2 * 8 + j) * 64 + e4 * 4];
                        c[j] = fmaf(qf[4*e4+0], kv.x, c[j]);
                        c[j] = fmaf(qf[4*e4+1], kv.y, c[j]);
                        c[j] = fmaf(qf[4*e4+2], kv.z, c[j]);
                        c[j] = fmaf(qf[4*e4+3], kv.w, c[j]);
                    }
                }
#pragma unroll
                for (int j = 0; j < 8; j++) {
                    mx = fmaxf(mx, c[j]);
                    if (i8 == 0) r[j] = c[j];
                    else         r[j] = __fadd_rn(r[j], c[j]);
                }
            }

            // write prefetched chunk into the other wave-private buffer
            float* dst = &ldsK[wu][(s_cur + 1) & 1][lslot];
            *(float4*)(dst)      = pf0;
            *(float4*)(dst + 16) = pf1;
            *(float4*)(dst + 32) = pf2;
            *(float4*)(dst + 48) = pf3;
        }

        // ---- readlane groups i8 = 6..15 (keys lf*128 + 48..127) ----
#pragma unroll 1
        for (int i8 = 6; i8 < 16; ++i8) {
            // next group in the global readlane sequence (tail: reload)
            int nlf = lf, ni8 = i8 + 1;
            if (ni8 == 16) {
                if (lf < 3) { nlf = lf + 1; ni8 = 6; }
                else        { nlf = 3;      ni8 = 15; }
            }
            const int kn = nlf * 128 + ni8 * 8;
            float4 A1 = *(const float4*)(gld + (size_t)kn * HE);
            float4 B1 = *(const float4*)(gld + (size_t)(kn + 4) * HE);

            float c[8];
#pragma unroll
            for (int j = 0; j < 8; ++j) c[j] = 0.f;
            // keys j=0..3 from A0, j=4..7 from B0 (R8-exact, j outer)
#pragma unroll
            for (int j = 0; j < 4; ++j) {
#pragma unroll
                for (int e4 = 0; e4 < 16; ++e4) {
                    const int ln = j * 16 + e4;
                    c[j] = fmaf(qf[4*e4+0], rdlane(A0.x, ln), c[j]);
                    c[j] = fmaf(qf[4*e4+1], rdlane(A0.y, ln), c[j]);
                    c[j] = fmaf(qf[4*e4+2], rdlane(A0.z, ln), c[j]);
                    c[j] = fmaf(qf[4*e4+3], rdlane(A0.w, ln), c[j]);
                }
            }
#pragma unroll
            for (int j = 0; j < 4; ++j) {
#pragma unroll
                for (int e4 = 0; e4 < 16; ++e4) {
                    const int ln = j * 16 + e4;
                    c[4+j] = fmaf(qf[4*e4+0], rdlane(B0.x, ln), c[4+j]);
                    c[4+j] = fmaf(qf[4*e4+1], rdlane(B0.y, ln), c[4+j]);
                    c[4+j] = fmaf(qf[4*e4+2], rdlane(B0.z, ln), c[4+j]);
                    c[4+j] = fmaf(qf[4*e4+3], rdlane(B0.w, ln), c[4+j]);
                }
            }
#pragma unroll
            for (int j = 0; j < 8; ++j) {
                mx = fmaxf(mx, c[j]);
                r[j] = __fadd_rn(r[j], c[j]);   // i8 >= 6 here, never init
            }
            A0 = A1; B0 = B1;   // vmcnt wait lands here, after compute
        }

        blk[lf] = __fadd_rn(
            __fadd_rn(__fadd_rn(r[0], r[1]), __fadd_rn(r[2], r[3])),
            __fadd_rn(__fadd_rn(r[4], r[5]), __fadd_rn(r[6], r[7])));
    }
    const float sub = __fadd_rn(__fadd_rn(blk[0], blk[1]),
                                __fadd_rn(blk[2], blk[3]));

    smx[w][lq] = mx; ssub[w][lq] = sub;
    __syncthreads();
    if (w == 0) {
        const float m_all = fmaxf(fmaxf(smx[0][lq], smx[1][lq]),
                                  fmaxf(smx[2][lq], smx[3][lq]));
        const float s2048 = __fadd_rn(__fadd_rn(ssub[0][lq], ssub[1][lq]),
                                      __fadd_rn(ssub[2][lq], ssub[3][lq]));
        const float mean = __fmul_rn(s2048, 0.00048828125f);  // /2048 exact
        m32[((size_t)bh << 11) + l]  = __fsub_rn(m_all, mean);
        maxs[((size_t)bh << 11) + l] = m_all;
    }
}

// ---------- B: descending sort, ties -> lower index first -----------------
__global__ __launch_bounds__(256)
void sort_rank(const float* __restrict__ m32, int* __restrict__ rank) {
    __shared__ unsigned int k1[2048];
    __shared__ int pay[2048];
    const int bh = blockIdx.x;
    const int t = threadIdx.x;
    for (int i = t; i < 2048; i += 256) {
        unsigned int u = __float_as_uint(m32[((size_t)bh << 11) + i]);
        u = (u & 0x80000000u) ? ~u : (u | 0x80000000u);
        k1[i] = u; pay[i] = i;
    }
    __syncthreads();
    for (int k = 2; k <= 2048; k <<= 1) {
        for (int j = k >> 1; j > 0; j >>= 1) {
            for (int i = t; i < 2048; i += 256) {
                const int ixj = i ^ j;
                if (ixj > i) {
                    unsigned int a1 = k1[i], c1 = k1[ixj];
                    int pa = pay[i], pc = pay[ixj];
                    const bool pre = (a1 > c1) || (a1 == c1 && pa < pc);
                    const bool dir = ((i & k) == 0);
                    if (dir != pre) {
                        k1[i] = c1; k1[ixj] = a1;
                        pay[i] = pc; pay[ixj] = pa;
                    }
                }
            }
            __syncthreads();
        }
    }
    for (int i = t; i < 2048; i += 256)
        rank[((size_t)bh << 11) + pay[i]] = i;   // inverse permutation
}

// ---------- C: bf16 MFMA flash (two-pass softmax), scatter by rank --------
// Wave w owns 16 queries (rows lt*64 + w*16 .. +15) over the FULL S range.
// Per 64-s chunk: QK via mfma_16x16x32_bf16 (8), exp, P->LDS (A-layout),
// PV via mfma (8). K staged [s][e], V staged transposed [d][s], pitch 72
// bf16 (16B-aligned rows, bank-spread).
__global__ __launch_bounds__(256, 2)
void flash_mfma(const float* __restrict__ Q, const float* __restrict__ K,
                const float* __restrict__ V, const float* __restrict__ maxs,
                const int* __restrict__ rank, float* __restrict__ out) {
    __shared__ unsigned short ldsK[64 * 72];        // 9216 B
    __shared__ unsigned short ldsVT[64 * 72];       // 9216 B  (V transposed)
    __shared__ unsigned short ldsP[4 * 16 * 72];    // 9216 B  (per-wave P)

    const int bid = blockIdx.x;          // 512
    const int lt = bid & 31, bh = bid >> 5;
    const int h = bh & 7, b = bh >> 3;
    const int t = threadIdx.x, lane = t & 63, w = t >> 6;
    const int quad = lane >> 4, cl = lane & 15;

    const size_t kvbase = (((size_t)b * SS) * HH + h) * EE;

    // Q A-frags: A[m=cl][k=quad*8+j (+32*ef)]
    bf16x8 qa[2];
    {
        const float* qp = Q + (((size_t)b * LL + (lt * 64 + w * 16 + cl)) * HH + h) * EE
                          + quad * 8;
#pragma unroll
        for (int ef = 0; ef < 2; ++ef) {
            float4 a0 = *(const float4*)(qp + ef * 32);
            float4 a1 = *(const float4*)(qp + ef * 32 + 4);
            short* s = (short*)&qa[ef];
            s[0] = (short)f2bf(a0.x); s[1] = (short)f2bf(a0.y);
            s[2] = (short)f2bf(a0.z); s[3] = (short)f2bf(a0.w);
            s[4] = (short)f2bf(a1.x); s[5] = (short)f2bf(a1.y);
            s[6] = (short)f2bf(a1.z); s[7] = (short)f2bf(a1.w);
        }
    }

    // per-lane row constants (rows quad*4+reg)
    float negpm[4];
    int rk[4];
#pragma unroll
    for (int reg = 0; reg < 4; ++reg) {
        const int qg = lt * 64 + w * 16 + quad * 4 + reg;
        negpm[reg] = -0.125f * maxs[((size_t)bh << 11) + qg];
        rk[reg]    = rank[((size_t)bh << 11) + qg];
    }

    f32x4 accO[4];
#pragma unroll
    for (int nt = 0; nt < 4; ++nt) accO[nt] = (f32x4){0.f, 0.f, 0.f, 0.f};
    float ell[4] = {0.f, 0.f, 0.f, 0.f};

    const int pbase = w * (16 * 72);

#pragma unroll 1
    for (int c0 = 0; c0 < SS; c0 += 64) {
        __syncthreads();
        // ---- stage K[s][e] -> bf16, row-major pitch 72 ----
        {
            const int row = t >> 2, col0 = (t & 3) * 16;
            const float* gp = K + kvbase + (size_t)(c0 + row) * HE + col0;
            float4 f0 = ((const float4*)gp)[0];
            float4 f1 = ((const float4*)gp)[1];
            float4 f2 = ((const float4*)gp)[2];
            float4 f3 = ((const float4*)gp)[3];
            u16x8 w0 = { f2bf(f0.x), f2bf(f0.y), f2bf(f0.z), f2bf(f0.w),
                         f2bf(f1.x), f2bf(f1.y), f2bf(f1.z), f2bf(f1.w) };
            u16x8 w1 = { f2bf(f2.x), f2bf(f2.y), f2bf(f2.z), f2bf(f2.w),
                         f2bf(f3.x), f2bf(f3.y), f2bf(f3.z), f2bf(f3.w) };
            *(u16x8*)&ldsK[row * 72 + col0]     = w0;
            *(u16x8*)&ldsK[row * 72 + col0 + 8] = w1;
        }
        // ---- stage V transposed: VT[d][s] bf16, pitch 72 ----
        {
            const int s0 = (t & 15) * 4, d0 = (t >> 4) * 4;
            const float* gv = V + kvbase + (size_t)(c0 + s0) * HE + d0;
            float4 v0 = *(const float4*)(gv);
            float4 v1 = *(const float4*)(gv + HE);
            float4 v2 = *(const float4*)(gv + 2 * HE);
            float4 v3 = *(const float4*)(gv + 3 * HE);
            u16x4 p0 = { f2bf(v0.x), f2bf(v1.x), f2bf(v2.x), f2bf(v3.x) };
            u16x4 p1 = { f2bf(v0.y), f2bf(v1.y), f2bf(v2.y), f2bf(v3.y) };
            u16x4 p2 = { f2bf(v0.z), f2bf(v1.z), f2bf(v2.z), f2bf(v3.z) };
            u16x4 p3 = { f2bf(v0.w), f2bf(v1.w), f2bf(v2.w), f2bf(v3.w) };
            *(u16x4*)&ldsVT[(d0 + 0) * 72 + s0] = p0;
            *(u16x4*)&ldsVT[(d0 + 1) * 72 + s0] = p1;
            *(u16x4*)&ldsVT[(d0 + 2) * 72 + s0] = p2;
            *(u16x4*)&ldsVT[(d0 + 3) * 72 + s0] = p3;
        }
        __syncthreads();

        // ---- QK^T: S[m=q16][n=s64] = A(Q) x B(K), B[k=e][n=s]=K[s][e] ----
        f32x4 Sc[4];
#pragma unroll
        for (int nt = 0; nt < 4; ++nt) {
            bf16x8 bk0 = *(const bf16x8*)&ldsK[(nt * 16 + cl) * 72 + quad * 8];
            bf16x8 bk1 = *(const bf16x8*)&ldsK[(nt * 16 + cl) * 72 + quad * 8 + 32];
            f32x4 z = (f32x4){0.f, 0.f, 0.f, 0.f};
            z = __builtin_amdgcn_mfma_f32_16x16x32_bf16(qa[0], bk0, z, 0, 0, 0);
            z = __builtin_amdgcn_mfma_f32_16x16x32_bf16(qa[1], bk1, z, 0, 0, 0);
            Sc[nt] = z;
        }

        // ---- softmax numerator + P (bf16) into A-layout LDS ----
#pragma unroll
        for (int nt = 0; nt < 4; ++nt) {
#pragma unroll
            for (int reg = 0; reg < 4; ++reg) {
                const float p = __expf(fmaf(Sc[nt][reg], 0.125f, negpm[reg]));
                ell[reg] += p;
                ldsP[pbase + (quad * 4 + reg) * 72 + nt * 16 + cl] = f2bf(p);
            }
        }

        // ---- PV: O[m=q16][n=d64] += A(P) x B(V), B[k=s][n=d]=VT[d][s] ----
        bf16x8 pa0 = *(const bf16x8*)&ldsP[pbase + cl * 72 + quad * 8];
        bf16x8 pa1 = *(const bf16x8*)&ldsP[pbase + cl * 72 + quad * 8 + 32];
#pragma unroll
        for (int nt = 0; nt < 4; ++nt) {
            bf16x8 bv0 = *(const bf16x8*)&ldsVT[(nt * 16 + cl) * 72 + quad * 8];
            bf16x8 bv1 = *(const bf16x8*)&ldsVT[(nt * 16 + cl) * 72 + quad * 8 + 32];
            accO[nt] = __builtin_amdgcn_mfma_f32_16x16x32_bf16(pa0, bv0, accO[nt], 0, 0, 0);
            accO[nt] = __builtin_amdgcn_mfma_f32_16x16x32_bf16(pa1, bv1, accO[nt], 0, 0, 0);
        }
    }

    // ---- ell: reduce across the 16 lanes sharing each row (within quad) ----
#pragma unroll
    for (int reg = 0; reg < 4; ++reg) {
        float e = ell[reg];
        e += __shfl_xor(e, 1);
        e += __shfl_xor(e, 2);
        e += __shfl_xor(e, 4);
        e += __shfl_xor(e, 8);
        ell[reg] = 1.0f / e;
    }

    // ---- scatter O rows by rank ----
#pragma unroll
    for (int reg = 0; reg < 4; ++reg) {
        float* orow = out + (((size_t)b * LL + rk[reg]) * HH + h) * DD;
#pragma unroll
        for (int nt = 0; nt < 4; ++nt)
            orow[nt * 16 + cl] = accO[nt][reg] * ell[reg];
    }
}

extern "C" void kernel_launch(void* const* d_in, const int* in_sizes, int n_in,
                              void* d_out, int out_size, void* d_ws, size_t ws_size,
                              hipStream_t stream) {
    const float* Q = (const float*)d_in[0];
    const float* K = (const float*)d_in[1];
    const float* V = (const float*)d_in[2];
    float* out = (float*)d_out;

    float* m32  = (float*)d_ws;                          // 128 KB
    int*   rank = (int*)((char*)d_ws + 131072);          // 128 KB
    float* maxs = (float*)((char*)d_ws + 262144);        // 128 KB

    msp_blas<<<BB * HH * (LL / 64), 256, 0, stream>>>(Q, K, m32, maxs);
    sort_rank<<<BB * HH, 256, 0, stream>>>(m32, rank);
    flash_mfma<<<BB * HH * (LL / 64), 256, 0, stream>>>(Q, K, V, maxs, rank, out);
}

// Round 11
// 421.932 us; speedup vs baseline: 1.5769x; 1.0430x over previous
//
#include <hip/hip_runtime.h>
#include <math.h>

#define BB 2
#define LL 2048
#define SS 2048
#define HH 8
#define EE 64
#define DD 64
#define HE (HH * EE)   // 512
// softmax scale = 1/sqrt(E) = 0.125

// ws layout (384 KB):
//   [0, 128K)     : m32  (B*H*L floats) -- BLAS-grid fp32 M_sp (bit-exact)
//   [128K, 256K)  : rank (B*H*L ints)
//   [256K, 384K)  : maxs (B*H*L floats)

typedef __attribute__((ext_vector_type(8))) short   bf16x8;   // MFMA A/B frag
typedef __attribute__((ext_vector_type(4))) float   f32x4;    // MFMA C/D frag
typedef __attribute__((ext_vector_type(8))) unsigned short u16x8;
typedef __attribute__((ext_vector_type(4))) unsigned short u16x4;

__device__ __forceinline__ unsigned short f2bf(float x) {   // fp32 -> bf16 RNE
    unsigned int u = __float_as_uint(x);
    return (unsigned short)((u + 0x7FFFu + ((u >> 16) & 1u)) >> 16);
}

__device__ __forceinline__ float rdlane(float v, int lane) { // bit-exact copy
    return __uint_as_float(
        (unsigned)__builtin_amdgcn_readlane((int)__float_as_uint(v), lane));
}

// ---------- A: BLAS-grid fp32 M_sp, INTERLEAVED hybrid (LDS + readlane) ---
// Arithmetic sequence IDENTICAL to the verified kernel:
// score = sequential fmaf chain e=0..63 asc, single accumulator; r[j] chain
// over i8=0..15 STRICTLY ASCENDING per lf; blk[lf] = exact-halves tree;
// sub = ((blk0+blk1)+(blk2+blk3)); s2048 = ((sub0+sub1)+(sub2+sub3)).
// DO NOT REORDER. Both group bodies are the verified R1/R8 code verbatim;
// only each group's broadcast SOURCE differs (chains are indifferent).
//
// R10 lesson: lf-scale phases serialize the two pipes (all 8 waves/CU hit
// the LDS phase in lockstep -> 4x oversubscribed, then idle; times ADD:
// 123+136 = 259 ~ 271 measured). Fix: interleave at i8 granularity.
// Per lf: i8 {0,3,6,9,12,15} from per-wave LDS dbuf (8-key chunks),
// i8 {1,2,4,5,7,8,10,11,13,14} via R8 readlane groups, processed 0..15
// ascending. LDS demand = 37.5% of each wave's timeline, drifting waves
// fill each other's gaps. Model: LDS/CU 295k cyc (123us, hidden) under
// VALU/SIMD 323k cyc (135us ideal).
// launch_bounds(256,2): 128-VGPR cap (R10 fit at 128, fewer staging regs
// here); grid 512 = 2 blocks/CU = 2 waves/SIMD (R1-proven envelope).
__global__ __launch_bounds__(256, 2)
void msp_blas(const float* __restrict__ Q, const float* __restrict__ K,
              float* __restrict__ m32, float* __restrict__ maxs) {
#pragma clang fp contract(off)
    __shared__ __align__(16) float ldsK[4][2][8 * 64];    // 16 KB, per-wave dbuf
    __shared__ float smx[4][64], ssub[4][64];             // 2 KB

    const int bid = blockIdx.x;          // B*H*32 = 512
    const int lt = bid & 31, bh = bid >> 5;
    const int h = bh & 7, b = bh >> 3;
    const int t = threadIdx.x, lq = t & 63, w = t >> 6;
    const int l = lt * 64 + lq;

    float qf[64];
    const float4* qrow = (const float4*)(Q + (((size_t)b * LL + l) * HH + h) * EE);
#pragma unroll
    for (int i = 0; i < 16; i++) {
        float4 v = qrow[i];
        qf[4*i] = v.x; qf[4*i+1] = v.y; qf[4*i+2] = v.z; qf[4*i+3] = v.w;
    }

    const int wu = __builtin_amdgcn_readfirstlane(w);
    const float* Kb = K + (((size_t)b * SS) * HH + h) * EE;

    // readlane-path load base (R8): 4 keys per dwordx4, coalesced
    const float* gld = Kb + (size_t)(w * 512 + (lq >> 4)) * HE + (lq & 15) * 4;
    // LDS-path staging base: 8-key groups; lane covers key (lq>>3),
    // floats (lq&7)*8 .. +7 (two float4 loads)
    const float* gstage = Kb + (size_t)(wu * 512 + (lq >> 3)) * HE + (lq & 7) * 8;
    const int lslot = (lq >> 3) * 64 + (lq & 7) * 8;

    // LDS-group sequence gL=0..23: lf=gL/6, m=gL%6, i8=min(3m,15)
    // RL-group  sequence gR=0..39: lf=gR/10, m=gR%10, i8=m+1+(m>>1)
    float4 p0, p1;
    {   // prologue: LDS group 0 (keys 0..7) -> buf 0
        p0 = *(const float4*)(gstage);
        p1 = *(const float4*)(gstage + 4);
        float* dst = &ldsK[wu][0][lslot];
        *(float4*)(dst)     = p0;
        *(float4*)(dst + 4) = p1;
    }
    // prologue: RL group 0 = (lf0, i8=1), keys 8..15
    float4 A0 = *(const float4*)(gld + (size_t)8 * HE);
    float4 B0 = *(const float4*)(gld + (size_t)12 * HE);

    int gL = 1, gR = 1, cur = 0;
    float mx = -1e30f;
    float blk[4];
#pragma unroll 1
    for (int lf = 0; lf < 4; ++lf) {
        float r[8];
#pragma unroll 1
        for (int seg = 0; seg < 6; ++seg) {
            // ---- L group: seg<5 -> i8=3*seg ; seg==5 -> i8=15 ----
            {
                // stage next LDS group (clamp tail: reload, discarded)
                const int g  = (gL < 23) ? gL : 23;
                const int lfn = g / 6, mn = g % 6;
                const int i8n = (mn < 5) ? 3 * mn : 15;
                const float* sp = gstage + (size_t)(lfn * 128 + i8n * 8) * HE;
                p0 = *(const float4*)(sp);
                p1 = *(const float4*)(sp + 4);

                const float* kbp = &ldsK[wu][cur][0];
                float c[8];
#pragma unroll
                for (int j = 0; j < 8; j++) c[j] = 0.f;
#pragma unroll
                for (int e4 = 0; e4 < 16; ++e4) {
#pragma unroll
                    for (int j = 0; j < 8; j++) {
                        const float4 kv = *(const float4*)&kbp[j * 64 + e4 * 4];
                        c[j] = fmaf(qf[4*e4+0], kv.x, c[j]);
                        c[j] = fmaf(qf[4*e4+1], kv.y, c[j]);
                        c[j] = fmaf(qf[4*e4+2], kv.z, c[j]);
                        c[j] = fmaf(qf[4*e4+3], kv.w, c[j]);
                    }
                }
#pragma unroll
                for (int j = 0; j < 8; j++) {
                    mx = fmaxf(mx, c[j]);
                    if (seg == 0) r[j] = c[j];             // i8==0: init
                    else          r[j] = __fadd_rn(r[j], c[j]);
                }

                float* dst = &ldsK[wu][cur ^ 1][lslot];
                *(float4*)(dst)     = p0;
                *(float4*)(dst + 4) = p1;
                cur ^= 1; ++gL;
            }
            if (seg == 5) break;   // i8=15 is the last group of this lf

            // ---- R groups: i8 = 3*seg+1, 3*seg+2 ----
#pragma unroll 1
            for (int u = 0; u < 2; ++u) {
                const int g  = (gR < 39) ? gR : 39;
                const int lfn = g / 10, mn = g % 10;
                const int i8n = mn + 1 + (mn >> 1);
                const int kn = lfn * 128 + i8n * 8;
                float4 A1 = *(const float4*)(gld + (size_t)kn * HE);
                float4 B1 = *(const float4*)(gld + (size_t)(kn + 4) * HE);

                float c[8];
#pragma unroll
                for (int j = 0; j < 8; ++j) c[j] = 0.f;
#pragma unroll
                for (int j = 0; j < 4; ++j) {
#pragma unroll
                    for (int e4 = 0; e4 < 16; ++e4) {
                        const int ln = j * 16 + e4;
                        c[j] = fmaf(qf[4*e4+0], rdlane(A0.x, ln), c[j]);
                        c[j] = fmaf(qf[4*e4+1], rdlane(A0.y, ln), c[j]);
                        c[j] = fmaf(qf[4*e4+2], rdlane(A0.z, ln), c[j]);
                        c[j] = fmaf(qf[4*e4+3], rdlane(A0.w, ln), c[j]);
                    }
                }
#pragma unroll
                for (int j = 0; j < 4; ++j) {
#pragma unroll
                    for (int e4 = 0; e4 < 16; ++e4) {
                        const int ln = j * 16 + e4;
                        c[4+j] = fmaf(qf[4*e4+0], rdlane(B0.x, ln), c[4+j]);
                        c[4+j] = fmaf(qf[4*e4+1], rdlane(B0.y, ln), c[4+j]);
                        c[4+j] = fmaf(qf[4*e4+2], rdlane(B0.z, ln), c[4+j]);
                        c[4+j] = fmaf(qf[4*e4+3], rdlane(B0.w, ln), c[4+j]);
                    }
                }
#pragma unroll
                for (int j = 0; j < 8; ++j) {
                    mx = fmaxf(mx, c[j]);
                    r[j] = __fadd_rn(r[j], c[j]);          // never first
                }
                A0 = A1; B0 = B1; ++gR;
            }
        }

        blk[lf] = __fadd_rn(
            __fadd_rn(__fadd_rn(r[0], r[1]), __fadd_rn(r[2], r[3])),
            __fadd_rn(__fadd_rn(r[4], r[5]), __fadd_rn(r[6], r[7])));
    }
    const float sub = __fadd_rn(__fadd_rn(blk[0], blk[1]),
                                __fadd_rn(blk[2], blk[3]));

    smx[w][lq] = mx; ssub[w][lq] = sub;
    __syncthreads();
    if (w == 0) {
        const float m_all = fmaxf(fmaxf(smx[0][lq], smx[1][lq]),
                                  fmaxf(smx[2][lq], smx[3][lq]));
        const float s2048 = __fadd_rn(__fadd_rn(ssub[0][lq], ssub[1][lq]),
                                      __fadd_rn(ssub[2][lq], ssub[3][lq]));
        const float mean = __fmul_rn(s2048, 0.00048828125f);  // /2048 exact
        m32[((size_t)bh << 11) + l]  = __fsub_rn(m_all, mean);
        maxs[((size_t)bh << 11) + l] = m_all;
    }
}

// ---------- B: descending sort, ties -> lower index first -----------------
__global__ __launch_bounds__(256)
void sort_rank(const float* __restrict__ m32, int* __restrict__ rank) {
    __shared__ unsigned int k1[2048];
    __shared__ int pay[2048];
    const int bh = blockIdx.x;
    const int t = threadIdx.x;
    for (int i = t; i < 2048; i += 256) {
        unsigned int u = __float_as_uint(m32[((size_t)bh << 11) + i]);
        u = (u & 0x80000000u) ? ~u : (u | 0x80000000u);
        k1[i] = u; pay[i] = i;
    }
    __syncthreads();
    for (int k = 2; k <= 2048; k <<= 1) {
        for (int j = k >> 1; j > 0; j >>= 1) {
            for (int i = t; i < 2048; i += 256) {
                const int ixj = i ^ j;
                if (ixj > i) {
                    unsigned int a1 = k1[i], c1 = k1[ixj];
                    int pa = pay[i], pc = pay[ixj];
                    const bool pre = (a1 > c1) || (a1 == c1 && pa < pc);
                    const bool dir = ((i & k) == 0);
                    if (dir != pre) {
                        k1[i] = c1; k1[ixj] = a1;
                        pay[i] = pc; pay[ixj] = pa;
                    }
                }
            }
            __syncthreads();
        }
    }
    for (int i = t; i < 2048; i += 256)
        rank[((size_t)bh << 11) + pay[i]] = i;   // inverse permutation
}

// ---------- C: bf16 MFMA flash (two-pass softmax), scatter by rank --------
// Wave w owns 16 queries (rows lt*64 + w*16 .. +15) over the FULL S range.
// Per 64-s chunk: QK via mfma_16x16x32_bf16 (8), exp, P->LDS (A-layout),
// PV via mfma (8). K staged [s][e], V staged transposed [d][s], pitch 72
// bf16 (16B-aligned rows, bank-spread).
__global__ __launch_bounds__(256, 2)
void flash_mfma(const float* __restrict__ Q, const float* __restrict__ K,
                const float* __restrict__ V, const float* __restrict__ maxs,
                const int* __restrict__ rank, float* __restrict__ out) {
    __shared__ unsigned short ldsK[64 * 72];        // 9216 B
    __shared__ unsigned short ldsVT[64 * 72];       // 9216 B  (V transposed)
    __shared__ unsigned short ldsP[4 * 16 * 72];    // 9216 B  (per-wave P)

    const int bid = blockIdx.x;          // 512
    const int lt = bid & 31, bh = bid >> 5;
    const int h = bh & 7, b = bh >> 3;
    const int t = threadIdx.x, lane = t & 63, w = t >> 6;
    const int quad = lane >> 4, cl = lane & 15;

    const size_t kvbase = (((size_t)b * SS) * HH + h) * EE;

    // Q A-frags: A[m=cl][k=quad*8+j (+32*ef)]
    bf16x8 qa[2];
    {
        const float* qp = Q + (((size_t)b * LL + (lt * 64 + w * 16 + cl)) * HH + h) * EE
                          + quad * 8;
#pragma unroll
        for (int ef = 0; ef < 2; ++ef) {
            float4 a0 = *(const float4*)(qp + ef * 32);
            float4 a1 = *(const float4*)(qp + ef * 32 + 4);
            short* s = (short*)&qa[ef];
            s[0] = (short)f2bf(a0.x); s[1] = (short)f2bf(a0.y);
            s[2] = (short)f2bf(a0.z); s[3] = (short)f2bf(a0.w);
            s[4] = (short)f2bf(a1.x); s[5] = (short)f2bf(a1.y);
            s[6] = (short)f2bf(a1.z); s[7] = (short)f2bf(a1.w);
        }
    }

    // per-lane row constants (rows quad*4+reg)
    float negpm[4];
    int rk[4];
#pragma unroll
    for (int reg = 0; reg < 4; ++reg) {
        const int qg = lt * 64 + w * 16 + quad * 4 + reg;
        negpm[reg] = -0.125f * maxs[((size_t)bh << 11) + qg];
        rk[reg]    = rank[((size_t)bh << 11) + qg];
    }

    f32x4 accO[4];
#pragma unroll
    for (int nt = 0; nt < 4; ++nt) accO[nt] = (f32x4){0.f, 0.f, 0.f, 0.f};
    float ell[4] = {0.f, 0.f, 0.f, 0.f};

    const int pbase = w * (16 * 72);

#pragma unroll 1
    for (int c0 = 0; c0 < SS; c0 += 64) {
        __syncthreads();
        // ---- stage K[s][e] -> bf16, row-major pitch 72 ----
        {
            const int row = t >> 2, col0 = (t & 3) * 16;
            const float* gp = K + kvbase + (size_t)(c0 + row) * HE + col0;
            float4 f0 = ((const float4*)gp)[0];
            float4 f1 = ((const float4*)gp)[1];
            float4 f2 = ((const float4*)gp)[2];
            float4 f3 = ((const float4*)gp)[3];
            u16x8 w0 = { f2bf(f0.x), f2bf(f0.y), f2bf(f0.z), f2bf(f0.w),
                         f2bf(f1.x), f2bf(f1.y), f2bf(f1.z), f2bf(f1.w) };
            u16x8 w1 = { f2bf(f2.x), f2bf(f2.y), f2bf(f2.z), f2bf(f2.w),
                         f2bf(f3.x), f2bf(f3.y), f2bf(f3.z), f2bf(f3.w) };
            *(u16x8*)&ldsK[row * 72 + col0]     = w0;
            *(u16x8*)&ldsK[row * 72 + col0 + 8] = w1;
        }
        // ---- stage V transposed: VT[d][s] bf16, pitch 72 ----
        {
            const int s0 = (t & 15) * 4, d0 = (t >> 4) * 4;
            const float* gv = V + kvbase + (size_t)(c0 + s0) * HE + d0;
            float4 v0 = *(const float4*)(gv);
            float4 v1 = *(const float4*)(gv + HE);
            float4 v2 = *(const float4*)(gv + 2 * HE);
            float4 v3 = *(const float4*)(gv + 3 * HE);
            u16x4 p0 = { f2bf(v0.x), f2bf(v1.x), f2bf(v2.x), f2bf(v3.x) };
            u16x4 p1 = { f2bf(v0.y), f2bf(v1.y), f2bf(v2.y), f2bf(v3.y) };
            u16x4 p2 = { f2bf(v0.z), f2bf(v1.z), f2bf(v2.z), f2bf(v3.z) };
            u16x4 p3 = { f2bf(v0.w), f2bf(v1.w), f2bf(v2.w), f2bf(v3.w) };
            *(u16x4*)&ldsVT[(d0 + 0) * 72 + s0] = p0;
            *(u16x4*)&ldsVT[(d0 + 1) * 72 + s0] = p1;
            *(u16x4*)&ldsVT[(d0 + 2) * 72 + s0] = p2;
            *(u16x4*)&ldsVT[(d0 + 3) * 72 + s0] = p3;
        }
        __syncthreads();

        // ---- QK^T: S[m=q16][n=s64] = A(Q) x B(K), B[k=e][n=s]=K[s][e] ----
        f32x4 Sc[4];
#pragma unroll
        for (int nt = 0; nt < 4; ++nt) {
            bf16x8 bk0 = *(const bf16x8*)&ldsK[(nt * 16 + cl) * 72 + quad * 8];
            bf16x8 bk1 = *(const bf16x8*)&ldsK[(nt * 16 + cl) * 72 + quad * 8 + 32];
            f32x4 z = (f32x4){0.f, 0.f, 0.f, 0.f};
            z = __builtin_amdgcn_mfma_f32_16x16x32_bf16(qa[0], bk0, z, 0, 0, 0);
            z = __builtin_amdgcn_mfma_f32_16x16x32_bf16(qa[1], bk1, z, 0, 0, 0);
            Sc[nt] = z;
        }

        // ---- softmax numerator + P (bf16) into A-layout LDS ----
#pragma unroll
        for (int nt = 0; nt < 4; ++nt) {
#pragma unroll
            for (int reg = 0; reg < 4; ++reg) {
                const float p = __expf(fmaf(Sc[nt][reg], 0.125f, negpm[reg]));
                ell[reg] += p;
                ldsP[pbase + (quad * 4 + reg) * 72 + nt * 16 + cl] = f2bf(p);
            }
        }

        // ---- PV: O[m=q16][n=d64] += A(P) x B(V), B[k=s][n=d]=VT[d][s] ----
        bf16x8 pa0 = *(const bf16x8*)&ldsP[pbase + cl * 72 + quad * 8];
        bf16x8 pa1 = *(const bf16x8*)&ldsP[pbase + cl * 72 + quad * 8 + 32];
#pragma unroll
        for (int nt = 0; nt < 4; ++nt) {
            bf16x8 bv0 = *(const bf16x8*)&ldsVT[(nt * 16 + cl) * 72 + quad * 8];
            bf16x8 bv1 = *(const bf16x8*)&ldsVT[(nt * 16 + cl) * 72 + quad * 8 + 32];
            accO[nt] = __builtin_amdgcn_mfma_f32_16x16x32_bf16(pa0, bv0, accO[nt], 0, 0, 0);
            accO[nt] = __builtin_amdgcn_mfma_f32_16x16x32_bf16(pa1, bv1, accO[nt], 0, 0, 0);
        }
    }

    // ---- ell: reduce across the 16 lanes sharing each row (within quad) ----
#pragma unroll
    for (int reg = 0; reg < 4; ++reg) {
        float e = ell[reg];
        e += __shfl_xor(e, 1);
        e += __shfl_xor(e, 2);
        e += __shfl_xor(e, 4);
        e += __shfl_xor(e, 8);
        ell[reg] = 1.0f / e;
    }

    // ---- scatter O rows by rank ----
#pragma unroll
    for (int reg = 0; reg < 4; ++reg) {
        float* orow = out + (((size_t)b * LL + rk[reg]) * HH + h) * DD;
#pragma unroll
        for (int nt = 0; nt < 4; ++nt)
            orow[nt * 16 + cl] = accO[nt][reg] * ell[reg];
    }
}

extern "C" void kernel_launch(void* const* d_in, const int* in_sizes, int n_in,
                              void* d_out, int out_size, void* d_ws, size_t ws_size,
                              hipStream_t stream) {
    const float* Q = (const float*)d_in[0];
    const float* K = (const float*)d_in[1];
    const float* V = (const float*)d_in[2];
    float* out = (float*)d_out;

    float* m32  = (float*)d_ws;                          // 128 KB
    int*   rank = (int*)((char*)d_ws + 131072);          // 128 KB
    float* maxs = (float*)((char*)d_ws + 262144);        // 128 KB

    msp_blas<<<BB * HH * (LL / 64), 256, 0, stream>>>(Q, K, m32, maxs);
    sort_rank<<<BB * HH, 256, 0, stream>>>(m32, rank);
    flash_mfma<<<BB * HH * (LL / 64), 256, 0, stream>>>(Q, K, V, maxs, rank, out);
}

// Round 12
// 409.595 us; speedup vs baseline: 1.6244x; 1.0301x over previous
//
#include <hip/hip_runtime.h>
#include <math.h>

#define BB 2
#define LL 2048
#define SS 2048
#define HH 8
#define EE 64
#define DD 64
#define HE (HH * EE)   // 512
// softmax scale = 1/sqrt(E) = 0.125

// ws layout (384 KB):
//   [0, 128K)     : m32  (B*H*L floats) -- BLAS-grid fp32 M_sp (bit-exact)
//   [128K, 256K)  : rank (B*H*L ints)
//   [256K, 384K)  : maxs (B*H*L floats)

typedef __attribute__((ext_vector_type(8))) short   bf16x8;   // MFMA A/B frag
typedef __attribute__((ext_vector_type(4))) float   f32x4;    // MFMA C/D frag
typedef __attribute__((ext_vector_type(8))) unsigned short u16x8;
typedef __attribute__((ext_vector_type(4))) unsigned short u16x4;

__device__ __forceinline__ unsigned short f2bf(float x) {   // fp32 -> bf16 RNE
    unsigned int u = __float_as_uint(x);
    return (unsigned short)((u + 0x7FFFu + ((u >> 16) & 1u)) >> 16);
}

__device__ __forceinline__ float rdlane(float v, int lane) { // bit-exact copy
    return __uint_as_float(
        (unsigned)__builtin_amdgcn_readlane((int)__float_as_uint(v), lane));
}

// ---------- A: BLAS-grid fp32 M_sp, VMEM + readlane broadcast (ILP-tuned) -
// Arithmetic sequence IDENTICAL to the verified kernel:
// score = sequential fmaf chain e=0..63 asc, single accumulator per key
// (each c[j] chain receives its updates in ascending-e order: e4 ascending,
// and within e4 the x,y,z,w components = e+0,1,2,3. The e4/comp/j loop
// nesting only interleaves INDEPENDENT chains); r[j] chain over i8=0..15
// sequential; blk[lf] = exact-halves tree over r[0..7];
// sub = ((blk0+blk1)+(blk2+blk3)); s2048 = ((sub0+sub1)+(sub2+sub3)).
// DO NOT REORDER. readlane is a bit-exact copy.
//
// R8 (218us, proven): j-outer/e4-inner -> each c[j] is a serial 64-deep
// dependent fmaf chain; measured 6.9 cyc per (rdlane+fmaf) pair vs the
// 4-cyc issue floor -> ~40% dependency-stall slack. R11 hybrid (241us)
// lost to R8 -> LDS supplement is dead. This version: SAME instructions,
// ILP-restructured order (e4 outer, component next, j inner): consecutive
// updates of one chain are now 8 instrs apart (7 other chains between),
// hiding the ~4cyc fmaf dep latency. Pure scheduling change, bit-exact.
// launch_bounds(256,2): 128-VGPR cap; est ~100 (R8 was 84), 2 waves/SIMD.
__global__ __launch_bounds__(256, 2)
void msp_blas(const float* __restrict__ Q, const float* __restrict__ K,
              float* __restrict__ m32, float* __restrict__ maxs) {
#pragma clang fp contract(off)
    const int bid = blockIdx.x;          // B*H*32 = 512
    const int lt = bid & 31, bh = bid >> 5;
    const int h = bh & 7, b = bh >> 3;
    const int t = threadIdx.x, lq = t & 63, w = t >> 6;
    const int l = lt * 64 + lq;

    float qf[64];
    const float4* qrow = (const float4*)(Q + (((size_t)b * LL + l) * HH + h) * EE);
#pragma unroll
    for (int i = 0; i < 16; i++) {
        float4 v = qrow[i];
        qf[4*i] = v.x; qf[4*i+1] = v.y; qf[4*i+2] = v.z; qf[4*i+3] = v.w;
    }

    // wave w owns keys [512w, 512w+512) (same blk mapping as verified kernel)
    const float* Kw = K + (((size_t)b * SS) * HH + h) * EE + (size_t)w * 512 * HE;
    // per-lane load base: key +(lq>>4), floats 4*(lq&15)..+3 (coalesced 256B)
    const float* gld = Kw + (size_t)(lq >> 4) * HE + (lq & 15) * 4;

    // double-buffered 8-key groups: A = keys kc..kc+3, B = keys kc+4..kc+7
    float4 A0 = *(const float4*)(gld);
    float4 B0 = *(const float4*)(gld + 4 * HE);

    float mx = -1e30f;
    float blk[4];
#pragma unroll 1
    for (int lf = 0; lf < 4; ++lf) {
        float r[8];
#pragma unroll 1
        for (int i8 = 0; i8 < 16; ++i8) {
            const int kc = lf * 128 + i8 * 8;            // group base key
            const int kn = (kc < 504) ? kc + 8 : 504;    // next (tail: reload)

            // issue next-group loads; consumed only at the A0=A1 copy below
            float4 A1 = *(const float4*)(gld + (size_t)kn * HE);
            float4 B1 = *(const float4*)(gld + (size_t)(kn + 4) * HE);

            float c[8];
#pragma unroll
            for (int j = 0; j < 8; ++j) c[j] = 0.f;
            // ILP order: e4 outer, component next, j inner. Each chain c[j]
            // is updated every 8 instructions by a strictly e-ascending
            // sequence (x,y,z,w within each e4) -- bit-exact vs R8/verified.
#pragma unroll
            for (int e4 = 0; e4 < 16; ++e4) {
#pragma unroll
                for (int j = 0; j < 4; ++j)
                    c[j]   = fmaf(qf[4*e4+0], rdlane(A0.x, j*16+e4), c[j]);
#pragma unroll
                for (int j = 0; j < 4; ++j)
                    c[4+j] = fmaf(qf[4*e4+0], rdlane(B0.x, j*16+e4), c[4+j]);
#pragma unroll
                for (int j = 0; j < 4; ++j)
                    c[j]   = fmaf(qf[4*e4+1], rdlane(A0.y, j*16+e4), c[j]);
#pragma unroll
                for (int j = 0; j < 4; ++j)
                    c[4+j] = fmaf(qf[4*e4+1], rdlane(B0.y, j*16+e4), c[4+j]);
#pragma unroll
                for (int j = 0; j < 4; ++j)
                    c[j]   = fmaf(qf[4*e4+2], rdlane(A0.z, j*16+e4), c[j]);
#pragma unroll
                for (int j = 0; j < 4; ++j)
                    c[4+j] = fmaf(qf[4*e4+2], rdlane(B0.z, j*16+e4), c[4+j]);
#pragma unroll
                for (int j = 0; j < 4; ++j)
                    c[j]   = fmaf(qf[4*e4+3], rdlane(A0.w, j*16+e4), c[j]);
#pragma unroll
                for (int j = 0; j < 4; ++j)
                    c[4+j] = fmaf(qf[4*e4+3], rdlane(B0.w, j*16+e4), c[4+j]);
            }
#pragma unroll
            for (int j = 0; j < 8; ++j) {
                mx = fmaxf(mx, c[j]);
                if (i8 == 0) r[j] = c[j];
                else         r[j] = __fadd_rn(r[j], c[j]);
            }
            A0 = A1; B0 = B1;   // vmcnt wait lands here, after compute
        }
        blk[lf] = __fadd_rn(
            __fadd_rn(__fadd_rn(r[0], r[1]), __fadd_rn(r[2], r[3])),
            __fadd_rn(__fadd_rn(r[4], r[5]), __fadd_rn(r[6], r[7])));
    }
    const float sub = __fadd_rn(__fadd_rn(blk[0], blk[1]),
                                __fadd_rn(blk[2], blk[3]));

    __shared__ float smx[4][64], ssub[4][64];
    smx[w][lq] = mx; ssub[w][lq] = sub;
    __syncthreads();
    if (w == 0) {
        const float m_all = fmaxf(fmaxf(smx[0][lq], smx[1][lq]),
                                  fmaxf(smx[2][lq], smx[3][lq]));
        const float s2048 = __fadd_rn(__fadd_rn(ssub[0][lq], ssub[1][lq]),
                                      __fadd_rn(ssub[2][lq], ssub[3][lq]));
        const float mean = __fmul_rn(s2048, 0.00048828125f);  // /2048 exact
        m32[((size_t)bh << 11) + l]  = __fsub_rn(m_all, mean);
        maxs[((size_t)bh << 11) + l] = m_all;
    }
}

// ---------- B: descending sort, ties -> lower index first -----------------
__global__ __launch_bounds__(256)
void sort_rank(const float* __restrict__ m32, int* __restrict__ rank) {
    __shared__ unsigned int k1[2048];
    __shared__ int pay[2048];
    const int bh = blockIdx.x;
    const int t = threadIdx.x;
    for (int i = t; i < 2048; i += 256) {
        unsigned int u = __float_as_uint(m32[((size_t)bh << 11) + i]);
        u = (u & 0x80000000u) ? ~u : (u | 0x80000000u);
        k1[i] = u; pay[i] = i;
    }
    __syncthreads();
    for (int k = 2; k <= 2048; k <<= 1) {
        for (int j = k >> 1; j > 0; j >>= 1) {
            for (int i = t; i < 2048; i += 256) {
                const int ixj = i ^ j;
                if (ixj > i) {
                    unsigned int a1 = k1[i], c1 = k1[ixj];
                    int pa = pay[i], pc = pay[ixj];
                    const bool pre = (a1 > c1) || (a1 == c1 && pa < pc);
                    const bool dir = ((i & k) == 0);
                    if (dir != pre) {
                        k1[i] = c1; k1[ixj] = a1;
                        pay[i] = pc; pay[ixj] = pa;
                    }
                }
            }
            __syncthreads();
        }
    }
    for (int i = t; i < 2048; i += 256)
        rank[((size_t)bh << 11) + pay[i]] = i;   // inverse permutation
}

// ---------- C: bf16 MFMA flash (two-pass softmax), scatter by rank --------
// Wave w owns 16 queries (rows lt*64 + w*16 .. +15) over the FULL S range.
// Per 64-s chunk: QK via mfma_16x16x32_bf16 (8), exp, P->LDS (A-layout),
// PV via mfma (8). K staged [s][e], V staged transposed [d][s], pitch 72
// bf16 (16B-aligned rows, bank-spread).
__global__ __launch_bounds__(256, 2)
void flash_mfma(const float* __restrict__ Q, const float* __restrict__ K,
                const float* __restrict__ V, const float* __restrict__ maxs,
                const int* __restrict__ rank, float* __restrict__ out) {
    __shared__ unsigned short ldsK[64 * 72];        // 9216 B
    __shared__ unsigned short ldsVT[64 * 72];       // 9216 B  (V transposed)
    __shared__ unsigned short ldsP[4 * 16 * 72];    // 9216 B  (per-wave P)

    const int bid = blockIdx.x;          // 512
    const int lt = bid & 31, bh = bid >> 5;
    const int h = bh & 7, b = bh >> 3;
    const int t = threadIdx.x, lane = t & 63, w = t >> 6;
    const int quad = lane >> 4, cl = lane & 15;

    const size_t kvbase = (((size_t)b * SS) * HH + h) * EE;

    // Q A-frags: A[m=cl][k=quad*8+j (+32*ef)]
    bf16x8 qa[2];
    {
        const float* qp = Q + (((size_t)b * LL + (lt * 64 + w * 16 + cl)) * HH + h) * EE
                          + quad * 8;
#pragma unroll
        for (int ef = 0; ef < 2; ++ef) {
            float4 a0 = *(const float4*)(qp + ef * 32);
            float4 a1 = *(const float4*)(qp + ef * 32 + 4);
            short* s = (short*)&qa[ef];
            s[0] = (short)f2bf(a0.x); s[1] = (short)f2bf(a0.y);
            s[2] = (short)f2bf(a0.z); s[3] = (short)f2bf(a0.w);
            s[4] = (short)f2bf(a1.x); s[5] = (short)f2bf(a1.y);
            s[6] = (short)f2bf(a1.z); s[7] = (short)f2bf(a1.w);
        }
    }

    // per-lane row constants (rows quad*4+reg)
    float negpm[4];
    int rk[4];
#pragma unroll
    for (int reg = 0; reg < 4; ++reg) {
        const int qg = lt * 64 + w * 16 + quad * 4 + reg;
        negpm[reg] = -0.125f * maxs[((size_t)bh << 11) + qg];
        rk[reg]    = rank[((size_t)bh << 11) + qg];
    }

    f32x4 accO[4];
#pragma unroll
    for (int nt = 0; nt < 4; ++nt) accO[nt] = (f32x4){0.f, 0.f, 0.f, 0.f};
    float ell[4] = {0.f, 0.f, 0.f, 0.f};

    const int pbase = w * (16 * 72);

#pragma unroll 1
    for (int c0 = 0; c0 < SS; c0 += 64) {
        __syncthreads();
        // ---- stage K[s][e] -> bf16, row-major pitch 72 ----
        {
            const int row = t >> 2, col0 = (t & 3) * 16;
            const float* gp = K + kvbase + (size_t)(c0 + row) * HE + col0;
            float4 f0 = ((const float4*)gp)[0];
            float4 f1 = ((const float4*)gp)[1];
            float4 f2 = ((const float4*)gp)[2];
            float4 f3 = ((const float4*)gp)[3];
            u16x8 w0 = { f2bf(f0.x), f2bf(f0.y), f2bf(f0.z), f2bf(f0.w),
                         f2bf(f1.x), f2bf(f1.y), f2bf(f1.z), f2bf(f1.w) };
            u16x8 w1 = { f2bf(f2.x), f2bf(f2.y), f2bf(f2.z), f2bf(f2.w),
                         f2bf(f3.x), f2bf(f3.y), f2bf(f3.z), f2bf(f3.w) };
            *(u16x8*)&ldsK[row * 72 + col0]     = w0;
            *(u16x8*)&ldsK[row * 72 + col0 + 8] = w1;
        }
        // ---- stage V transposed: VT[d][s] bf16, pitch 72 ----
        {
            const int s0 = (t & 15) * 4, d0 = (t >> 4) * 4;
            const float* gv = V + kvbase + (size_t)(c0 + s0) * HE + d0;
            float4 v0 = *(const float4*)(gv);
            float4 v1 = *(const float4*)(gv + HE);
            float4 v2 = *(const float4*)(gv + 2 * HE);
            float4 v3 = *(const float4*)(gv + 3 * HE);
            u16x4 p0 = { f2bf(v0.x), f2bf(v1.x), f2bf(v2.x), f2bf(v3.x) };
            u16x4 p1 = { f2bf(v0.y), f2bf(v1.y), f2bf(v2.y), f2bf(v3.y) };
            u16x4 p2 = { f2bf(v0.z), f2bf(v1.z), f2bf(v2.z), f2bf(v3.z) };
            u16x4 p3 = { f2bf(v0.w), f2bf(v1.w), f2bf(v2.w), f2bf(v3.w) };
            *(u16x4*)&ldsVT[(d0 + 0) * 72 + s0] = p0;
            *(u16x4*)&ldsVT[(d0 + 1) * 72 + s0] = p1;
            *(u16x4*)&ldsVT[(d0 + 2) * 72 + s0] = p2;
            *(u16x4*)&ldsVT[(d0 + 3) * 72 + s0] = p3;
        }
        __syncthreads();

        // ---- QK^T: S[m=q16][n=s64] = A(Q) x B(K), B[k=e][n=s]=K[s][e] ----
        f32x4 Sc[4];
#pragma unroll
        for (int nt = 0; nt < 4; ++nt) {
            bf16x8 bk0 = *(const bf16x8*)&ldsK[(nt * 16 + cl) * 72 + quad * 8];
            bf16x8 bk1 = *(const bf16x8*)&ldsK[(nt * 16 + cl) * 72 + quad * 8 + 32];
            f32x4 z = (f32x4){0.f, 0.f, 0.f, 0.f};
            z = __builtin_amdgcn_mfma_f32_16x16x32_bf16(qa[0], bk0, z, 0, 0, 0);
            z = __builtin_amdgcn_mfma_f32_16x16x32_bf16(qa[1], bk1, z, 0, 0, 0);
            Sc[nt] = z;
        }

        // ---- softmax numerator + P (bf16) into A-layout LDS ----
#pragma unroll
        for (int nt = 0; nt < 4; ++nt) {
#pragma unroll
            for (int reg = 0; reg < 4; ++reg) {
                const float p = __expf(fmaf(Sc[nt][reg], 0.125f, negpm[reg]));
                ell[reg] += p;
                ldsP[pbase + (quad * 4 + reg) * 72 + nt * 16 + cl] = f2bf(p);
            }
        }

        // ---- PV: O[m=q16][n=d64] += A(P) x B(V), B[k=s][n=d]=VT[d][s] ----
        bf16x8 pa0 = *(const bf16x8*)&ldsP[pbase + cl * 72 + quad * 8];
        bf16x8 pa1 = *(const bf16x8*)&ldsP[pbase + cl * 72 + quad * 8 + 32];
#pragma unroll
        for (int nt = 0; nt < 4; ++nt) {
            bf16x8 bv0 = *(const bf16x8*)&ldsVT[(nt * 16 + cl) * 72 + quad * 8];
            bf16x8 bv1 = *(const bf16x8*)&ldsVT[(nt * 16 + cl) * 72 + quad * 8 + 32];
            accO[nt] = __builtin_amdgcn_mfma_f32_16x16x32_bf16(pa0, bv0, accO[nt], 0, 0, 0);
            accO[nt] = __builtin_amdgcn_mfma_f32_16x16x32_bf16(pa1, bv1, accO[nt], 0, 0, 0);
        }
    }

    // ---- ell: reduce across the 16 lanes sharing each row (within quad) ----
#pragma unroll
    for (int reg = 0; reg < 4; ++reg) {
        float e = ell[reg];
        e += __shfl_xor(e, 1);
        e += __shfl_xor(e, 2);
        e += __shfl_xor(e, 4);
        e += __shfl_xor(e, 8);
        ell[reg] = 1.0f / e;
    }

    // ---- scatter O rows by rank ----
#pragma unroll
    for (int reg = 0; reg < 4; ++reg) {
        float* orow = out + (((size_t)b * LL + rk[reg]) * HH + h) * DD;
#pragma unroll
        for (int nt = 0; nt < 4; ++nt)
            orow[nt * 16 + cl] = accO[nt][reg] * ell[reg];
    }
}

extern "C" void kernel_launch(void* const* d_in, const int* in_sizes, int n_in,
                              void* d_out, int out_size, void* d_ws, size_t ws_size,
                              hipStream_t stream) {
    const float* Q = (const float*)d_in[0];
    const float* K = (const float*)d_in[1];
    const float* V = (const float*)d_in[2];
    float* out = (float*)d_out;

    float* m32  = (float*)d_ws;                          // 128 KB
    int*   rank = (int*)((char*)d_ws + 131072);          // 128 KB
    float* maxs = (float*)((char*)d_ws + 262144);        // 128 KB

    msp_blas<<<BB * HH * (LL / 64), 256, 0, stream>>>(Q, K, m32, maxs);
    sort_rank<<<BB * HH, 256, 0, stream>>>(m32, rank);
    flash_mfma<<<BB * HH * (LL / 64), 256, 0, stream>>>(Q, K, V, maxs, rank, out);
}